// Round 8
// baseline (93.744 us; speedup 1.0000x reference)
//
#include <hip/hip_runtime.h>
#include <hip/hip_bf16.h>
#include <stdint.h>

// Problem constants (B=16, S=1024, E=8 qubits -> 2^8 = 256 amplitudes).
#define NB 16
#define S_LEN 1024
#define E_Q 8

typedef float v4f __attribute__((ext_vector_type(4)));
typedef short v8s __attribute__((ext_vector_type(8)));
typedef int   v4i __attribute__((ext_vector_type(4)));

// ---------------------------------------------------------------------------
// Kernel 1: per-token cos/sin feature tables, INT8 (scale 127).
// Q-table 512 B/row [127cos|127sin]; K-table 768 B/row [127cos|127sin|-127cos]
// (2-chain no-spill MFMA form; R14 proved the 3-chain variant spills).
// ---------------------------------------------------------------------------
__global__ __launch_bounds__(256) void build_tables(
    const float* __restrict__ Q, const float* __restrict__ K,
    int8_t* __restrict__ Aq, int8_t* __restrict__ Kt)
{
    const int which = blockIdx.y;
    const float* X = which ? K : Q;

    const int tok = blockIdx.x * 16 + (threadIdx.x >> 4);
    const int hi  = threadIdx.x & 15;     // z bits 4..7
    const int zb  = hi * 16;

    const float* x = X + tok * E_Q;
    float xv[E_Q]; float sq = 0.f;
#pragma unroll
    for (int i = 0; i < E_Q; ++i) { xv[i] = x[i]; sq += xv[i] * xv[i]; }
    const float qsq = 0.25f * sq;

    // L at z = zb: low 4 bits 0 (sign +), high bits from `hi`.
    float L = xv[0] + xv[1] + xv[2] + xv[3];
#pragma unroll
    for (int i = 4; i < 8; ++i) L += ((hi >> (i - 4)) & 1) ? -xv[i] : xv[i];

    __align__(16) int8_t cb[16];
    __align__(16) int8_t sb[16];

    {   // n = 0, gray = 0
        const float phi = fmaf(-0.25f, L * L, fmaf(-0.5f, L, qsq));
        float s, c; __sincosf(phi, &s, &c);
        cb[0] = (int8_t)__float2int_rn(127.f * c);
        sb[0] = (int8_t)__float2int_rn(127.f * s);
    }
#pragma unroll
    for (int n = 1; n < 16; ++n) {
        const int g  = n ^ (n >> 1);
        const int gp = (n - 1) ^ ((n - 1) >> 1);
        const int t  = __builtin_ctz(g ^ gp);        // constant-folds
        const float twox = 2.0f * xv[t];
        L = ((g >> t) & 1) ? (L - twox) : (L + twox);
        const float phi = fmaf(-0.25f, L * L, fmaf(-0.5f, L, qsq));
        float s, c; __sincosf(phi, &s, &c);
        cb[g] = (int8_t)__float2int_rn(127.f * c);
        sb[g] = (int8_t)__float2int_rn(127.f * s);
    }

    if (which == 0) {
        int8_t* dst = Aq + (size_t)tok * 512;
        *(uint4*)(dst + zb)       = *(const uint4*)cb;
        *(uint4*)(dst + 256 + zb) = *(const uint4*)sb;
    } else {
        __align__(16) int8_t nb[16];
#pragma unroll
        for (int i = 0; i < 16; ++i) nb[i] = (int8_t)(-cb[i]);
        int8_t* dst = Kt + (size_t)tok * 768;
        *(uint4*)(dst + zb)       = *(const uint4*)cb;
        *(uint4*)(dst + 256 + zb) = *(const uint4*)sb;
        *(uint4*)(dst + 512 + zb) = *(const uint4*)nb;
    }
}

// ---------------------------------------------------------------------------
// Kernel 2: fused QK fidelity GEMM (i8) + nonlinearity + MFMA PV.
//
// R16: TRUE PHASE-SPLIT K-LOOP (T3 port at the proven granularity).
// Diagnosis: R9/R10/R11/R13/R15 all null because the loop was a 2-phase
// structure (barrier -> 12 reads -> 32 MFMA -> barrier); per learn_hip m233
// the 2-phase critical path is stage+vmcnt+barrier and neither traffic cuts
// nor setprio/swizzle respond in that regime. Port the 8-phase template's
// per-phase pattern (2 barriers per 16 MFMA, reads issued BEFORE the
// pre-MFMA barrier so ds latency hides under rendezvous; lgkmcnt(0) +
// sched_barrier(0) + setprio around the pure-MFMA cluster; counted vmcnt
// only at chunk boundaries, never 0 mid-loop):
//   per chunk c (64 B of K):  vmcnt(4); BAR;
//     ph0: read qF[0..3] + k-frags nj{0,1}; BAR; lgkm0; 16 MFMA; BAR;
//     ph1: read k-frags nj{2,3};            BAR; lgkm0; 16 MFMA; BAR;
//     STAGE(c+2)
// Everything else (tile 256x128, 8 waves as 4i x 2j, 2-chain accs = 128
// VGPRs, source-side swizzle, dbuf 2x32 KB, epilogue, partial stores) is
// byte-identical to R15 (passed).
// ---------------------------------------------------------------------------
__global__ __launch_bounds__(512, 2) void qk_pv(
    const int8_t* __restrict__ Aq, const int8_t* __restrict__ Kt,
    const float* __restrict__ V, float* __restrict__ part)
{
    __shared__ __align__(16) char smem[73984];
    // phase-2 aliases (valid after the post-K-loop barrier)
    uint16_t* lattn = (uint16_t*)smem;              // [256][136] bf16, rows=i
    uint16_t* lVt   = (uint16_t*)(smem + 69632);    // [16][136]  bf16 (V^T)

    const int jblk = blockIdx.x, iblk = blockIdx.y, b = blockIdx.z;
    const int tid  = threadIdx.x;
    const int lane = tid & 63, wv = tid >> 6;        // 8 waves
    const int wQi = wv >> 1, wKj = wv & 1;           // 4 i-quadrants x 2 j-halves
    const int r15 = lane & 15, qq = lane >> 4;

    // Staging offsets (source-side swizzle, p-invariant):
    const int ssw   = ((tid & 3) ^ ((tid >> 2) & 3)) << 4;
    const int baseA = (tid >> 2) * 512 + ssw;
    const int baseK = (tid >> 2) * 768 + ssw;
    const int ldst  = tid * 16;                      // linear LDS dest in tile

    // Fragment-read offsets (per-thread constants; buffer base varies by c&1)
    const int swz16 = (qq ^ (r15 & 3)) << 4;
    const int offA  = (wQi * 64 + r15) * 64 + swz16;
    const int offK0 = 16384 + (wKj * 64 + r15) * 64 + swz16;  // K1 at +8192

    const int8_t* gA = Aq + (size_t)(b * S_LEN + iblk * 256) * 512;
    const int8_t* gK = Kt + (size_t)(b * S_LEN + jblk * 128) * 768;

    v4i accRe[4][4], accIm[4][4];                    // [nj][mi]
#pragma unroll
    for (int nj = 0; nj < 4; ++nj)
#pragma unroll
        for (int mi = 0; mi < 4; ++mi) {
            accRe[nj][mi] = (v4i)0;
            accIm[nj][mi] = (v4i)0;
        }

#define STAGE(cc, bb)                                                          \
    {                                                                          \
        const int lb0 = (bb) * 32768 + ldst;                                   \
        __builtin_amdgcn_global_load_lds(                                      \
            (const __attribute__((address_space(1))) void*)(gA + (cc) * 64 + baseA), \
            (__attribute__((address_space(3))) void*)(smem + lb0), 16, 0, 0);  \
        __builtin_amdgcn_global_load_lds(                                      \
            (const __attribute__((address_space(1))) void*)(gA + (cc) * 64 + baseA + 65536), \
            (__attribute__((address_space(3))) void*)(smem + lb0 + 8192), 16, 0, 0); \
        __builtin_amdgcn_global_load_lds(                                      \
            (const __attribute__((address_space(1))) void*)(gK + (cc) * 64 + baseK), \
            (__attribute__((address_space(3))) void*)(smem + lb0 + 16384), 16, 0, 0); \
        __builtin_amdgcn_global_load_lds(                                      \
            (const __attribute__((address_space(1))) void*)(gK + 256 + (cc) * 64 + baseK), \
            (__attribute__((address_space(3))) void*)(smem + lb0 + 24576), 16, 0, 0); \
    }

    // Prologue: fill both buffers (8 loads in flight per thread).
    STAGE(0, 0)
    STAGE(1, 1)

#pragma unroll
    for (int c = 0; c < 8; ++c) {
        // Own chunk-c loads retired (newest 4 = chunk c+1 may stay in flight).
        if (c == 7) { asm volatile("s_waitcnt vmcnt(0)" ::: "memory"); }
        else        { asm volatile("s_waitcnt vmcnt(4)" ::: "memory"); }
        __builtin_amdgcn_s_barrier();                // buffer c ready
        asm volatile("" ::: "memory");

        const int8_t* lb = (const int8_t*)smem + ((c & 1) ? 32768 : 0);

        // ---- phase 0: reads (qF + nj{0,1}) BEFORE barrier; 16 MFMA after.
        v4i qF[4];
#pragma unroll
        for (int mi = 0; mi < 4; ++mi)
            qF[mi] = *(const v4i*)(lb + offA + mi * 1024);
        v4i k0a = *(const v4i*)(lb + offK0);
        v4i k1a = *(const v4i*)(lb + offK0 + 8192);
        v4i k0b = *(const v4i*)(lb + offK0 + 1024);
        v4i k1b = *(const v4i*)(lb + offK0 + 8192 + 1024);
        asm volatile("" ::: "memory");
        __builtin_amdgcn_s_barrier();                // ds latency hides here
        asm volatile("s_waitcnt lgkmcnt(0)" ::: "memory");
        __builtin_amdgcn_sched_barrier(0);           // no MFMA hoist (rule 18)
        __builtin_amdgcn_s_setprio(1);
#pragma unroll
        for (int mi = 0; mi < 4; ++mi) {
            accRe[0][mi] = __builtin_amdgcn_mfma_i32_16x16x64_i8(k0a, qF[mi], accRe[0][mi], 0, 0, 0);
            accIm[0][mi] = __builtin_amdgcn_mfma_i32_16x16x64_i8(k1a, qF[mi], accIm[0][mi], 0, 0, 0);
        }
#pragma unroll
        for (int mi = 0; mi < 4; ++mi) {
            accRe[1][mi] = __builtin_amdgcn_mfma_i32_16x16x64_i8(k0b, qF[mi], accRe[1][mi], 0, 0, 0);
            accIm[1][mi] = __builtin_amdgcn_mfma_i32_16x16x64_i8(k1b, qF[mi], accIm[1][mi], 0, 0, 0);
        }
        __builtin_amdgcn_s_setprio(0);
        asm volatile("" ::: "memory");
        __builtin_amdgcn_s_barrier();                // phase 0 done

        // ---- phase 1: reads (nj{2,3}) BEFORE barrier; 16 MFMA after.
        v4i k0c = *(const v4i*)(lb + offK0 + 2048);
        v4i k1c = *(const v4i*)(lb + offK0 + 8192 + 2048);
        v4i k0d = *(const v4i*)(lb + offK0 + 3072);
        v4i k1d = *(const v4i*)(lb + offK0 + 8192 + 3072);
        asm volatile("" ::: "memory");
        __builtin_amdgcn_s_barrier();
        asm volatile("s_waitcnt lgkmcnt(0)" ::: "memory");
        __builtin_amdgcn_sched_barrier(0);
        __builtin_amdgcn_s_setprio(1);
#pragma unroll
        for (int mi = 0; mi < 4; ++mi) {
            accRe[2][mi] = __builtin_amdgcn_mfma_i32_16x16x64_i8(k0c, qF[mi], accRe[2][mi], 0, 0, 0);
            accIm[2][mi] = __builtin_amdgcn_mfma_i32_16x16x64_i8(k1c, qF[mi], accIm[2][mi], 0, 0, 0);
        }
#pragma unroll
        for (int mi = 0; mi < 4; ++mi) {
            accRe[3][mi] = __builtin_amdgcn_mfma_i32_16x16x64_i8(k0d, qF[mi], accRe[3][mi], 0, 0, 0);
            accIm[3][mi] = __builtin_amdgcn_mfma_i32_16x16x64_i8(k1d, qF[mi], accIm[3][mi], 0, 0, 0);
        }
        __builtin_amdgcn_s_setprio(0);
        asm volatile("" ::: "memory");
        __builtin_amdgcn_s_barrier();                // all reads of buf done

        if (c < 6) STAGE(c + 2, c & 1)               // overwrite consumed buf
    }
#undef STAGE

    // ---- Epilogue: attn -> LDS bf16 [256][136]; V^T -> LDS bf16 [16][136] ----
    __syncthreads();                                 // full drain before alias

    // V tile load (deferred; latency hides under the conversions)
    float4 vreg;
    if (tid < 256)
        vreg = ((const float4*)(V + ((size_t)b * S_LEN + jblk * 128) * E_Q))[tid];

    const float sc2 = 3.0517578125e-05f / 260144641.0f;   // 2^-15 / 127^4
    // C^T layout: D row = j = wKj*64 + nj*16 + qq*4 + rg,  col = i = wQi*64
    // + mi*16 + r15.  4 consecutive j at fixed i -> one packed b64 store.
#pragma unroll
    for (int nj = 0; nj < 4; ++nj) {
#pragma unroll
        for (int mi = 0; mi < 4; ++mi) {
            uint64_t pk = 0;
#pragma unroll
            for (int rg = 0; rg < 4; ++rg) {
                const float rf  = (float)accRe[nj][mi][rg];
                const float imf = (float)accIm[nj][mi][rg];
                const float a   = fmaf(rf * rf + imf * imf, sc2, -1.0f);
                __hip_bfloat16 ab = __float2bfloat16(a);
                pk |= (uint64_t)(*(const uint16_t*)&ab) << (16 * rg);
            }
            const int i  = wQi * 64 + mi * 16 + r15;
            const int j0 = wKj * 64 + nj * 16 + qq * 4;
            *(uint64_t*)&lattn[i * 136 + j0] = pk;
        }
    }
    {   // V^T: lVt[e][j] = bf16(V[b][jblk*128+j][e]), e=0..7 from threads
        // 0..255; threads 256..511 zero rows 8..15 (B-frag garbage guard --
        // those rows feed only output cols 8..15 which are masked at store).
        if (tid < 256) {
            const int j = tid >> 1, eh = (tid & 1) * 4;
            const float vv[4] = {vreg.x, vreg.y, vreg.z, vreg.w};
#pragma unroll
            for (int c2 = 0; c2 < 4; ++c2) {
                __hip_bfloat16 vb = __float2bfloat16(vv[c2]);
                lVt[(eh + c2) * 136 + j] = *(const uint16_t*)&vb;
            }
        } else {
            const int j = (tid - 256) >> 1, eh = (tid & 1) * 4;
#pragma unroll
            for (int c2 = 0; c2 < 4; ++c2)
                lVt[(8 + eh + c2) * 136 + j] = 0;
        }
    }
    __syncthreads();

    // ---- Phase 2: out-tile = attnTile[256x128] @ Vt^T via bf16 MFMA ----
    v8s bfr[4];
#pragma unroll
    for (int ks3 = 0; ks3 < 4; ++ks3)
        bfr[ks3] = *(const v8s*)&lVt[r15 * 136 + ks3 * 32 + qq * 8];

    // Partial-output slab for this jblk: one writer per element, plain stores.
    float* pout = part + ((size_t)jblk << 17)                 // jblk * 131072
                + ((size_t)b << 13) + (iblk << 11);           // (b*1024+iblk*256)*8
#pragma unroll
    for (int mt = 0; mt < 2; ++mt) {
        const int rowbase = (wv * 2 + mt) * 16;               // 16 tiles cover 256 rows
        v4f accO = (v4f)0.f;
#pragma unroll
        for (int ks3 = 0; ks3 < 4; ++ks3) {
            const v8s af = *(const v8s*)&lattn[(rowbase + r15) * 136 + ks3 * 32 + qq * 8];
            accO = __builtin_amdgcn_mfma_f32_16x16x32_bf16(af, bfr[ks3], accO, 0, 0, 0);
        }
        if (r15 < E_Q) {
            const int i0 = rowbase + qq * 4;
#pragma unroll
            for (int rg = 0; rg < 4; ++rg)
                pout[(i0 + rg) * E_Q + r15] = accO[rg];
        }
    }
}

// ---------------------------------------------------------------------------
// Kernel 3: sum the 8 per-jblk partial slabs -> d_out. (unchanged)
// ---------------------------------------------------------------------------
__global__ __launch_bounds__(256) void reduce_out(
    const float4* __restrict__ part, float4* __restrict__ out)
{
    const int idx = blockIdx.x * 256 + threadIdx.x;          // 0..32767
    float4 s = part[idx];
#pragma unroll
    for (int k = 1; k < 8; ++k) {
        const float4 p = part[k * 32768 + idx];
        s.x += p.x; s.y += p.y; s.z += p.z; s.w += p.w;
    }
    out[idx] = s;
}

// ---------------------------------------------------------------------------
// Workspace layout (24 MB used):
//   [0,   8 MB)  Aq   : Q tables, [16*1024][512] i8  [cos|sin]
//   [8,  20 MB)  Kt   : K tables, [16*1024][768] i8  [cos|sin|-cos]
//   [20, 24 MB)  part : per-jblk PV partials, [8][16][1024][8] f32
// d_out written once per element by reduce_out (poison fully covered).
// ---------------------------------------------------------------------------
extern "C" void kernel_launch(void* const* d_in, const int* in_sizes, int n_in,
                              void* d_out, int out_size, void* d_ws, size_t ws_size,
                              hipStream_t stream) {
    const float* Q = (const float*)d_in[0];
    const float* K = (const float*)d_in[1];
    const float* V = (const float*)d_in[2];

    int8_t* Aq   = (int8_t*)d_ws;
    int8_t* Kt   = (int8_t*)((char*)d_ws + (size_t)8 * 1024 * 1024);
    float*  part = (float*)((char*)d_ws + (size_t)20 * 1024 * 1024);

    build_tables<<<dim3(NB * S_LEN / 16, 2), 256, 0, stream>>>(Q, K, Aq, Kt);
    qk_pv<<<dim3(S_LEN / 128, S_LEN / 256, NB), 512, 0, stream>>>(Aq, Kt, V, part);
    reduce_out<<<dim3(128), 256, 0, stream>>>((const float4*)part, (float4*)d_out);
}